// Round 3
// 1129.027 us; speedup vs baseline: 1.2355x; 1.2355x over previous
//
#include <hip/hip_runtime.h>
#include <math.h>

#define NH 16
#define SEQ 2048
#define DIM 128
#define NMEM 4096
#define TOPK 16
#define TQ 128         // queries per workgroup
#define KC 64          // keys per chunk
#define NCHUNK (NMEM / KC)   // 64
#define QST 132        // fp32 Q staging stride (r0)
#define KST 132        // fp32 K staging stride (r0)
#define SST 68         // sims stride (r0)
#define QBS 136        // bf16 Q stride (16B-aligned rows)
#define KBS 136        // bf16 K stride
#define QHS 132        // fp32 qhat stride (bank spread)
#define NTHR 512

typedef short bf16x8 __attribute__((ext_vector_type(8)));
typedef float f32x4  __attribute__((ext_vector_type(4)));

// pack two fp32 -> bf16x2 (round-to-nearest-even; finite inputs)
__device__ __forceinline__ unsigned f2bf2(float lo, float hi) {
    union { float f; unsigned u; } a, b;
    a.f = lo; b.f = hi;
    unsigned ra = (a.u + 0x7fffu + ((a.u >> 16) & 1u)) >> 16;
    unsigned rb = (b.u + 0x7fffu + ((b.u >> 16) & 1u)) & 0xffff0000u;
    return ra | rb;
}

__global__ __launch_bounds__(NTHR, 2)
void praxis_fused(const float* __restrict__ query,
                  const float* __restrict__ outputs,
                  const float* __restrict__ gate,
                  const float* __restrict__ kmem,
                  const float* __restrict__ vmem,
                  float* __restrict__ out)
{
    // Qb/Kb at identical offsets in phases q and a (persist across the q->a switch).
    __shared__ union SM {
        struct { unsigned short Qb[TQ * QBS]; unsigned short Kb[KC * KBS];
                 float Qs[TQ * QST]; } q;                                   // 119808 B
        struct { unsigned short Qb[TQ * QBS]; unsigned short Kb[KC * KBS];
                 float Ks[KC * KST]; float Sc[TQ * SST]; } a;               // 120832 B
        struct { float qh[TQ * QHS]; float fs[TQ][64]; int fi[TQ][64];
                 float tks[TQ][TOPK]; int tki[TQ][TOPK]; } b;               // 149504 B
    } sm;

    const int tid = threadIdx.x;
    const int h  = blockIdx.x >> 4;        // 16 q-tiles per head (SEQ/TQ)
    const int q0 = (blockIdx.x & 15) * TQ;

    const float* Qg = query + ((size_t)h * SEQ + q0) * DIM;
    const float* Kg = kmem + (size_t)h * NMEM * DIM;
    const float* Vg = vmem + (size_t)h * NMEM * DIM;

    // ---- stage Q tile raw (r0 code) ----
#pragma unroll
    for (int i = 0; i < 8; ++i) {
        int f4 = i * NTHR + tid;
        int row = f4 >> 5, col = f4 & 31;
        float4 v = *(const float4*)(Qg + (size_t)f4 * 4);
        *(float4*)(&sm.q.Qs[row * QST + col * 4]) = v;
    }
    __syncthreads();
    // ---- normalize Q rows with r0's EXACT reduction; emit bf16 Qb ----
    {
        int row = tid >> 2, part = tid & 3;
        float4 v[8];
        float ss = 0.f;
#pragma unroll
        for (int j = 0; j < 8; ++j) {
            v[j] = *(const float4*)(&sm.q.Qs[row * QST + part * 32 + j * 4]);
            ss = fmaf(v[j].x, v[j].x, ss); ss = fmaf(v[j].y, v[j].y, ss);
            ss = fmaf(v[j].z, v[j].z, ss); ss = fmaf(v[j].w, v[j].w, ss);
        }
        ss += __shfl_xor(ss, 1);
        ss += __shfl_xor(ss, 2);
        float inv = 1.0f / fmaxf(sqrtf(ss), 1e-6f);
#pragma unroll
        for (int j = 0; j < 8; ++j) {
            unsigned lo = f2bf2(v[j].x * inv, v[j].y * inv);
            unsigned hi = f2bf2(v[j].z * inv, v[j].w * inv);
            *(uint2*)(&sm.q.Qb[row * QBS + part * 32 + j * 4]) = make_uint2(lo, hi);
        }
    }
    __syncthreads();  // Qs dead; Ks staging (aliases Qs) may begin

    // per-thread running top-16 (SORTED ascending; ls[0] is the threshold)
    float ls[TOPK]; int li[TOPK];
#pragma unroll
    for (int t = 0; t < TOPK; ++t) { ls[t] = -1e30f; li[t] = 0; }

    // preload K chunk 0
    float4 kreg[4];
#pragma unroll
    for (int j = 0; j < 4; ++j)
        kreg[j] = *(const float4*)(Kg + (size_t)(j * NTHR + tid) * 4);

    for (int c = 0; c < NCHUNK; ++c) {
        // stage K chunk raw (r0 code)
#pragma unroll
        for (int j = 0; j < 4; ++j) {
            int f4 = j * NTHR + tid;
            int row = f4 >> 5, col = f4 & 31;
            *(float4*)(&sm.a.Ks[row * KST + col * 4]) = kreg[j];
        }
        __syncthreads();  // A

        // normalize K rows with r0's EXACT reduction (8 thr/key); emit bf16 Kb
        {
            int key = tid >> 3, part = tid & 7;
            float4 v[4];
            float ss = 0.f;
#pragma unroll
            for (int j = 0; j < 4; ++j) {
                v[j] = *(const float4*)(&sm.a.Ks[key * KST + part * 16 + j * 4]);
                ss = fmaf(v[j].x, v[j].x, ss); ss = fmaf(v[j].y, v[j].y, ss);
                ss = fmaf(v[j].z, v[j].z, ss); ss = fmaf(v[j].w, v[j].w, ss);
            }
            ss += __shfl_xor(ss, 1);
            ss += __shfl_xor(ss, 2);
            ss += __shfl_xor(ss, 4);
            float inv = 1.0f / fmaxf(sqrtf(ss), 1e-6f);
#pragma unroll
            for (int j = 0; j < 4; ++j) {
                unsigned lo = f2bf2(v[j].x * inv, v[j].y * inv);
                unsigned hi = f2bf2(v[j].z * inv, v[j].w * inv);
                *(uint2*)(&sm.a.Kb[key * KBS + part * 16 + j * 4]) = make_uint2(lo, hi);
            }
        }
        __syncthreads();  // B

        // prefetch next chunk (in flight across MFMA)
        if (c + 1 < NCHUNK) {
            const float* base = Kg + (size_t)(c + 1) * KC * DIM;
#pragma unroll
            for (int j = 0; j < 4; ++j)
                kreg[j] = *(const float4*)(base + (size_t)(j * NTHR + tid) * 4);
        }

        // ---- sims via MFMA: wave w -> q-rows [16w,16w+16) x all 64 keys ----
        // verified pattern (m89/m92): A,B loaded row-major linearly; C/D row=(lane>>4)*4+r, col=lane&15
        {
            const int w = tid >> 6, lane = tid & 63;
            const int l15 = lane & 15, lg = lane >> 4;
            const unsigned short* qb = &sm.a.Qb[(16 * w + l15) * QBS + lg * 8];
            const unsigned short* kb = &sm.a.Kb[l15 * KBS + lg * 8];
            f32x4 a0 = {0.f, 0.f, 0.f, 0.f};
            f32x4 a1 = a0, a2 = a0, a3 = a0;
#pragma unroll
            for (int kk = 0; kk < 4; ++kk) {
                bf16x8 af = *(const bf16x8*)(qb + kk * 32);
                bf16x8 b0 = *(const bf16x8*)(kb + kk * 32);
                bf16x8 b1 = *(const bf16x8*)(kb + 16 * KBS + kk * 32);
                bf16x8 b2 = *(const bf16x8*)(kb + 32 * KBS + kk * 32);
                bf16x8 b3 = *(const bf16x8*)(kb + 48 * KBS + kk * 32);
                a0 = __builtin_amdgcn_mfma_f32_16x16x32_bf16(af, b0, a0, 0, 0, 0);
                a1 = __builtin_amdgcn_mfma_f32_16x16x32_bf16(af, b1, a1, 0, 0, 0);
                a2 = __builtin_amdgcn_mfma_f32_16x16x32_bf16(af, b2, a2, 0, 0, 0);
                a3 = __builtin_amdgcn_mfma_f32_16x16x32_bf16(af, b3, a3, 0, 0, 0);
            }
            const int orow = 16 * w + lg * 4;
#pragma unroll
            for (int r = 0; r < 4; ++r) {
                float* sp = &sm.a.Sc[(orow + r) * SST + l15];
                sp[0]  = a0[r];
                sp[16] = a1[r];
                sp[32] = a2[r];
                sp[48] = a3[r];
            }
        }
        __syncthreads();  // C: Sc ready; Kb fully consumed

        // ---- top-k filter (r0 code; bf16-domain scores, selection slack is huge) ----
        {
            int row = tid >> 2, part = tid & 3;
            const float* scr = &sm.a.Sc[row * SST + part * 16];
            float4 vv[4];
#pragma unroll
            for (int g = 0; g < 4; ++g)
                vv[g] = *(const float4*)(scr + g * 4);
            float mnv = ls[0];
#pragma unroll
            for (int g = 0; g < 4; ++g) {
                float4 v = vv[g];
                int b0 = c * KC + part * 16 + g * 4;
                float m01 = fmaxf(v.x, v.y); int i01 = (v.x >= v.y) ? 0 : 1;
                float m23 = fmaxf(v.z, v.w); int i23 = (v.z >= v.w) ? 2 : 3;
                float m   = fmaxf(m01, m23); int im  = (m01 >= m23) ? i01 : i23;
                while (__ballot(m > mnv)) {
                    if (m > mnv) {
                        float s = m; int id = b0 + im;
                        bool bp = true;
#pragma unroll
                        for (int t = 0; t < TOPK - 1; ++t) {
                            bool bt = s > ls[t + 1];
                            float nv = bt ? ls[t + 1] : (bp ? s : ls[t]);
                            int   ni = bt ? li[t + 1] : (bp ? id : li[t]);
                            ls[t] = nv; li[t] = ni; bp = bt;
                        }
                        ls[TOPK - 1] = bp ? s : ls[TOPK - 1];
                        li[TOPK - 1] = bp ? id : li[TOPK - 1];
                        mnv = ls[0];
                        v.x = (im == 0) ? -3e38f : v.x;
                        v.y = (im == 1) ? -3e38f : v.y;
                        v.z = (im == 2) ? -3e38f : v.z;
                        v.w = (im == 3) ? -3e38f : v.w;
                        m01 = fmaxf(v.x, v.y); i01 = (v.x >= v.y) ? 0 : 1;
                        m23 = fmaxf(v.z, v.w); i23 = (v.z >= v.w) ? 2 : 3;
                        m   = fmaxf(m01, m23); im  = (m01 >= m23) ? i01 : i23;
                    }
                }
            }
        }
        // no barrier: next iter writes Ks (disjoint from Sc); barrier A orders Sc reuse
    }

    __syncthreads();  // repurpose LDS as phase-b
    // ---- build qhat = r0-bit-exact normalized q rows (fp32), dump pool indices ----
    {
        int row = tid >> 2, part = tid & 3;
        const float* qp = query + ((size_t)h * SEQ + q0 + row) * DIM + part * 32;
        float4 v[8];
        float ss = 0.f;
#pragma unroll
        for (int j = 0; j < 8; ++j) {
            v[j] = *(const float4*)(qp + j * 4);
            ss = fmaf(v[j].x, v[j].x, ss); ss = fmaf(v[j].y, v[j].y, ss);
            ss = fmaf(v[j].z, v[j].z, ss); ss = fmaf(v[j].w, v[j].w, ss);
        }
        ss += __shfl_xor(ss, 1);
        ss += __shfl_xor(ss, 2);
        float inv = 1.0f / fmaxf(sqrtf(ss), 1e-6f);
#pragma unroll
        for (int j = 0; j < 8; ++j) {
            float4 s;
            s.x = v[j].x * inv; s.y = v[j].y * inv;
            s.z = v[j].z * inv; s.w = v[j].w * inv;
            *(float4*)(&sm.b.qh[row * QHS + part * 32 + j * 4]) = s;
        }
#pragma unroll
        for (int t = 0; t < TOPK; ++t)
            sm.b.fi[row][part * TOPK + t] = li[t];
    }
    __syncthreads();
    // ---- rescore own 16 candidates with r0-bit-exact arithmetic ----
    // kinv: r0's 8x(16-dim fmaf chain) + ((s0+s1)+(s2+s3))+((s4+s5)+(s6+s7)) tree;
    // score: single 128-dim fmaf chain over qhat and (k * kinv) with per-element rounding.
    {
        int row = tid >> 2, part = tid & 3;
        const float* qh = &sm.b.qh[row * QHS];
#pragma unroll 1
        for (int t = 0; t < TOPK; ++t) {
            int idx = li[t];
            const float* kp = Kg + (size_t)idx * DIM;
            float sp[8];
#pragma unroll
            for (int p = 0; p < 8; ++p) {
                float s = 0.f;
#pragma unroll
                for (int j = 0; j < 4; ++j) {
                    float4 kv = *(const float4*)(kp + p * 16 + j * 4);
                    s = fmaf(kv.x, kv.x, s); s = fmaf(kv.y, kv.y, s);
                    s = fmaf(kv.z, kv.z, s); s = fmaf(kv.w, kv.w, s);
                }
                sp[p] = s;
            }
            float kss = ((sp[0] + sp[1]) + (sp[2] + sp[3])) +
                        ((sp[4] + sp[5]) + (sp[6] + sp[7]));
            float kinv = 1.0f / fmaxf(sqrtf(kss), 1e-6f);
            float acc = 0.f;
#pragma unroll
            for (int d4 = 0; d4 < 32; ++d4) {
                float4 qa = *(const float4*)(qh + d4 * 4);
                float4 kv = *(const float4*)(kp + d4 * 4);
                acc = fmaf(qa.x, kv.x * kinv, acc);
                acc = fmaf(qa.y, kv.y * kinv, acc);
                acc = fmaf(qa.z, kv.z * kinv, acc);
                acc = fmaf(qa.w, kv.w * kinv, acc);
            }
            sm.b.fs[row][part * TOPK + t] = acc;
        }
    }
    __syncthreads();
    // final selection: one wave per 16 rows; 16 rounds of wave-max over 64 cands.
    // Tie-break by SMALLEST index (matches jax.lax.top_k stability).
    {
        int wv = tid >> 6, lane = tid & 63;
        for (int rr = 0; rr < 16; ++rr) {
            int row = wv * 16 + rr;
            float s = sm.b.fs[row][lane];
            int  id = sm.b.fi[row][lane];
#pragma unroll 1
            for (int it = 0; it < TOPK; ++it) {
                float m = s;
#pragma unroll
                for (int off = 32; off >= 1; off >>= 1)
                    m = fmaxf(m, __shfl_xor(m, off));
                int cand = (s == m) ? id : 0x7FFFFFFF;
#pragma unroll
                for (int off = 32; off >= 1; off >>= 1)
                    cand = min(cand, __shfl_xor(cand, off));
                if (lane == 0) { sm.b.tks[row][it] = m; sm.b.tki[row][it] = cand; }
                if (s == m && id == cand) s = -3e38f;   // pool indices unique -> removes one
            }
        }
    }
    __syncthreads();
    // ---- epilogue: gather V, weighted sum (descending order = ref order), gate blend ----
    {
        int row = tid >> 2, part = tid & 3;
        float4 acc[8];
#pragma unroll
        for (int j = 0; j < 8; ++j) acc[j] = make_float4(0.f, 0.f, 0.f, 0.f);
#pragma unroll 1
        for (int t = 0; t < TOPK; ++t) {
            float s = sm.b.tks[row][t];
            int idx = sm.b.tki[row][t] & (NMEM - 1);
            const float* vp = Vg + (size_t)idx * DIM + part * 32;
#pragma unroll
            for (int j = 0; j < 8; ++j) {
                float4 v = *(const float4*)(vp + j * 4);
                acc[j].x = fmaf(s, v.x, acc[j].x);
                acc[j].y = fmaf(s, v.y, acc[j].y);
                acc[j].z = fmaf(s, v.z, acc[j].z);
                acc[j].w = fmaf(s, v.w, acc[j].w);
            }
        }
        float g = 1.0f / (1.0f + expf(-gate[h]));
        float og = 1.0f - g;
        size_t ob = ((size_t)h * SEQ + q0 + row) * DIM + part * 32;
#pragma unroll
        for (int j = 0; j < 8; ++j) {
            float4 o = *(const float4*)(outputs + ob + j * 4);
            float4 r;
            r.x = g * acc[j].x + og * o.x;
            r.y = g * acc[j].y + og * o.y;
            r.z = g * acc[j].z + og * o.z;
            r.w = g * acc[j].w + og * o.w;
            *(float4*)(out + ob + j * 4) = r;
        }
    }
}

extern "C" void kernel_launch(void* const* d_in, const int* in_sizes, int n_in,
                              void* d_out, int out_size, void* d_ws, size_t ws_size,
                              hipStream_t stream) {
    (void)in_sizes; (void)n_in; (void)out_size; (void)d_ws; (void)ws_size;
    const float* query   = (const float*)d_in[1];
    const float* outputs = (const float*)d_in[4];
    const float* gate    = (const float*)d_in[5];
    const float* kmem    = (const float*)d_in[6];
    const float* vmem    = (const float*)d_in[7];
    float* out = (float*)d_out;
    dim3 grid(NH * (SEQ / TQ));  // 256 workgroups, exactly 1 per CU
    praxis_fused<<<grid, NTHR, 0, stream>>>(query, outputs, gate, kmem, vmem, out);
}

// Round 4
// 976.179 us; speedup vs baseline: 1.4290x; 1.1566x over previous
//
#include <hip/hip_runtime.h>
#include <math.h>

#define NH 16
#define SEQ 2048
#define DIM 128
#define NMEM 4096
#define TOPK 16
#define TQ 128         // queries per workgroup
#define KC 64          // keys per chunk
#define NCHUNK (NMEM / KC)   // 64
#define QST 132        // fp32 Q staging stride (r0)
#define KST 132        // fp32 K staging stride (r0)
#define SST 68         // sims stride (r0)
#define QBS 136        // bf16 Q stride (16B-aligned rows)
#define KBS 136        // bf16 K stride
#define QHS 132        // fp32 qhat stride (bank spread)
#define NTHR 512

typedef short bf16x8 __attribute__((ext_vector_type(8)));
typedef float f32x4  __attribute__((ext_vector_type(4)));

// pack two fp32 -> bf16x2 (round-to-nearest-even; finite inputs)
__device__ __forceinline__ unsigned f2bf2(float lo, float hi) {
    union { float f; unsigned u; } a, b;
    a.f = lo; b.f = hi;
    unsigned ra = (a.u + 0x7fffu + ((a.u >> 16) & 1u)) >> 16;
    unsigned rb = (b.u + 0x7fffu + ((b.u >> 16) & 1u)) & 0xffff0000u;
    return ra | rb;
}

__global__ __launch_bounds__(NTHR, 2)
void praxis_fused(const float* __restrict__ query,
                  const float* __restrict__ outputs,
                  const float* __restrict__ gate,
                  const float* __restrict__ kmem,
                  const float* __restrict__ vmem,
                  float* __restrict__ out)
{
    // Qb/Kb at identical offsets in phases q and a (persist across the q->a switch).
    __shared__ union SM {
        struct { unsigned short Qb[TQ * QBS]; unsigned short Kb[KC * KBS];
                 float Qs[TQ * QST]; } q;                                   // 119808 B
        struct { unsigned short Qb[TQ * QBS]; unsigned short Kb[KC * KBS];
                 float Ks[KC * KST]; float Sc[TQ * SST]; } a;               // 120832 B
        struct { float qh[TQ * QHS]; float fs[TQ][64]; int fi[TQ][64];
                 float tks[TQ][TOPK]; int tki[TQ][TOPK]; } b;               // 149504 B
    } sm;

    const int tid = threadIdx.x;
    // XCD-aware bijective swizzle (nwg=256=8*32 exact): XCD x owns logical blocks
    // 32x..32x+31 = heads 2x,2x+1 -> per-XCD gather working set 4 MB (fits L2).
    const int lb = ((blockIdx.x & 7) << 5) | ((int)blockIdx.x >> 3);
    const int h  = lb >> 4;                // 16 q-tiles per head (SEQ/TQ)
    const int q0 = (lb & 15) * TQ;

    const float* Qg = query + ((size_t)h * SEQ + q0) * DIM;
    const float* Kg = kmem + (size_t)h * NMEM * DIM;
    const float* Vg = vmem + (size_t)h * NMEM * DIM;

    // ---- stage Q tile raw (r0 code) ----
#pragma unroll
    for (int i = 0; i < 8; ++i) {
        int f4 = i * NTHR + tid;
        int row = f4 >> 5, col = f4 & 31;
        float4 v = *(const float4*)(Qg + (size_t)f4 * 4);
        *(float4*)(&sm.q.Qs[row * QST + col * 4]) = v;
    }
    __syncthreads();
    // ---- normalize Q rows with r0's EXACT reduction; emit bf16 Qb ----
    {
        int row = tid >> 2, part = tid & 3;
        float4 v[8];
        float ss = 0.f;
#pragma unroll
        for (int j = 0; j < 8; ++j) {
            v[j] = *(const float4*)(&sm.q.Qs[row * QST + part * 32 + j * 4]);
            ss = fmaf(v[j].x, v[j].x, ss); ss = fmaf(v[j].y, v[j].y, ss);
            ss = fmaf(v[j].z, v[j].z, ss); ss = fmaf(v[j].w, v[j].w, ss);
        }
        ss += __shfl_xor(ss, 1);
        ss += __shfl_xor(ss, 2);
        float inv = 1.0f / fmaxf(sqrtf(ss), 1e-6f);
#pragma unroll
        for (int j = 0; j < 8; ++j) {
            unsigned lo = f2bf2(v[j].x * inv, v[j].y * inv);
            unsigned hi = f2bf2(v[j].z * inv, v[j].w * inv);
            *(uint2*)(&sm.q.Qb[row * QBS + part * 32 + j * 4]) = make_uint2(lo, hi);
        }
    }
    __syncthreads();  // Qs dead; Ks staging (aliases Qs) may begin

    // per-thread running top-16 (SORTED ascending; ls[0] is the threshold)
    float ls[TOPK]; int li[TOPK];
#pragma unroll
    for (int t = 0; t < TOPK; ++t) { ls[t] = -1e30f; li[t] = 0; }

    // preload K chunk 0
    float4 kreg[4];
#pragma unroll
    for (int j = 0; j < 4; ++j)
        kreg[j] = *(const float4*)(Kg + (size_t)(j * NTHR + tid) * 4);

    for (int c = 0; c < NCHUNK; ++c) {
        // stage K chunk raw (r0 code)
#pragma unroll
        for (int j = 0; j < 4; ++j) {
            int f4 = j * NTHR + tid;
            int row = f4 >> 5, col = f4 & 31;
            *(float4*)(&sm.a.Ks[row * KST + col * 4]) = kreg[j];
        }
        __syncthreads();  // A

        // normalize K rows with r0's EXACT reduction (8 thr/key); emit bf16 Kb
        {
            int key = tid >> 3, part = tid & 7;
            float4 v[4];
            float ss = 0.f;
#pragma unroll
            for (int j = 0; j < 4; ++j) {
                v[j] = *(const float4*)(&sm.a.Ks[key * KST + part * 16 + j * 4]);
                ss = fmaf(v[j].x, v[j].x, ss); ss = fmaf(v[j].y, v[j].y, ss);
                ss = fmaf(v[j].z, v[j].z, ss); ss = fmaf(v[j].w, v[j].w, ss);
            }
            ss += __shfl_xor(ss, 1);
            ss += __shfl_xor(ss, 2);
            ss += __shfl_xor(ss, 4);
            float inv = 1.0f / fmaxf(sqrtf(ss), 1e-6f);
#pragma unroll
            for (int j = 0; j < 4; ++j) {
                unsigned lo = f2bf2(v[j].x * inv, v[j].y * inv);
                unsigned hi = f2bf2(v[j].z * inv, v[j].w * inv);
                *(uint2*)(&sm.a.Kb[key * KBS + part * 16 + j * 4]) = make_uint2(lo, hi);
            }
        }
        __syncthreads();  // B

        // prefetch next chunk (in flight across MFMA)
        if (c + 1 < NCHUNK) {
            const float* base = Kg + (size_t)(c + 1) * KC * DIM;
#pragma unroll
            for (int j = 0; j < 4; ++j)
                kreg[j] = *(const float4*)(base + (size_t)(j * NTHR + tid) * 4);
        }

        // ---- sims via MFMA: wave w -> q-rows [16w,16w+16) x all 64 keys ----
        // verified pattern (m89/m92): A,B loaded row-major linearly; C/D row=(lane>>4)*4+r, col=lane&15
        {
            const int w = tid >> 6, lane = tid & 63;
            const int l15 = lane & 15, lg = lane >> 4;
            const unsigned short* qb = &sm.a.Qb[(16 * w + l15) * QBS + lg * 8];
            const unsigned short* kb = &sm.a.Kb[l15 * KBS + lg * 8];
            f32x4 a0 = {0.f, 0.f, 0.f, 0.f};
            f32x4 a1 = a0, a2 = a0, a3 = a0;
#pragma unroll
            for (int kk = 0; kk < 4; ++kk) {
                bf16x8 af = *(const bf16x8*)(qb + kk * 32);
                bf16x8 b0 = *(const bf16x8*)(kb + kk * 32);
                bf16x8 b1 = *(const bf16x8*)(kb + 16 * KBS + kk * 32);
                bf16x8 b2 = *(const bf16x8*)(kb + 32 * KBS + kk * 32);
                bf16x8 b3 = *(const bf16x8*)(kb + 48 * KBS + kk * 32);
                a0 = __builtin_amdgcn_mfma_f32_16x16x32_bf16(af, b0, a0, 0, 0, 0);
                a1 = __builtin_amdgcn_mfma_f32_16x16x32_bf16(af, b1, a1, 0, 0, 0);
                a2 = __builtin_amdgcn_mfma_f32_16x16x32_bf16(af, b2, a2, 0, 0, 0);
                a3 = __builtin_amdgcn_mfma_f32_16x16x32_bf16(af, b3, a3, 0, 0, 0);
            }
            const int orow = 16 * w + lg * 4;
#pragma unroll
            for (int r = 0; r < 4; ++r) {
                float* sp = &sm.a.Sc[(orow + r) * SST + l15];
                sp[0]  = a0[r];
                sp[16] = a1[r];
                sp[32] = a2[r];
                sp[48] = a3[r];
            }
        }
        __syncthreads();  // C: Sc ready; Kb fully consumed

        // ---- top-k filter (r0 code; bf16-domain scores, selection slack is huge) ----
        {
            int row = tid >> 2, part = tid & 3;
            const float* scr = &sm.a.Sc[row * SST + part * 16];
            float4 vv[4];
#pragma unroll
            for (int g = 0; g < 4; ++g)
                vv[g] = *(const float4*)(scr + g * 4);
            float mnv = ls[0];
#pragma unroll
            for (int g = 0; g < 4; ++g) {
                float4 v = vv[g];
                int b0 = c * KC + part * 16 + g * 4;
                float m01 = fmaxf(v.x, v.y); int i01 = (v.x >= v.y) ? 0 : 1;
                float m23 = fmaxf(v.z, v.w); int i23 = (v.z >= v.w) ? 2 : 3;
                float m   = fmaxf(m01, m23); int im  = (m01 >= m23) ? i01 : i23;
                while (__ballot(m > mnv)) {
                    if (m > mnv) {
                        float s = m; int id = b0 + im;
                        bool bp = true;
#pragma unroll
                        for (int t = 0; t < TOPK - 1; ++t) {
                            bool bt = s > ls[t + 1];
                            float nv = bt ? ls[t + 1] : (bp ? s : ls[t]);
                            int   ni = bt ? li[t + 1] : (bp ? id : li[t]);
                            ls[t] = nv; li[t] = ni; bp = bt;
                        }
                        ls[TOPK - 1] = bp ? s : ls[TOPK - 1];
                        li[TOPK - 1] = bp ? id : li[TOPK - 1];
                        mnv = ls[0];
                        v.x = (im == 0) ? -3e38f : v.x;
                        v.y = (im == 1) ? -3e38f : v.y;
                        v.z = (im == 2) ? -3e38f : v.z;
                        v.w = (im == 3) ? -3e38f : v.w;
                        m01 = fmaxf(v.x, v.y); i01 = (v.x >= v.y) ? 0 : 1;
                        m23 = fmaxf(v.z, v.w); i23 = (v.z >= v.w) ? 2 : 3;
                        m   = fmaxf(m01, m23); im  = (m01 >= m23) ? i01 : i23;
                    }
                }
            }
        }
        // no barrier: next iter writes Ks (disjoint from Sc); barrier A orders Sc reuse
    }

    __syncthreads();  // repurpose LDS as phase-b
    // ---- build qhat = r0-bit-exact normalized q rows (fp32), dump pool indices ----
    {
        int row = tid >> 2, part = tid & 3;
        const float* qp = query + ((size_t)h * SEQ + q0 + row) * DIM + part * 32;
        float4 v[8];
        float ss = 0.f;
#pragma unroll
        for (int j = 0; j < 8; ++j) {
            v[j] = *(const float4*)(qp + j * 4);
            ss = fmaf(v[j].x, v[j].x, ss); ss = fmaf(v[j].y, v[j].y, ss);
            ss = fmaf(v[j].z, v[j].z, ss); ss = fmaf(v[j].w, v[j].w, ss);
        }
        ss += __shfl_xor(ss, 1);
        ss += __shfl_xor(ss, 2);
        float inv = 1.0f / fmaxf(sqrtf(ss), 1e-6f);
#pragma unroll
        for (int j = 0; j < 8; ++j) {
            float4 s;
            s.x = v[j].x * inv; s.y = v[j].y * inv;
            s.z = v[j].z * inv; s.w = v[j].w * inv;
            *(float4*)(&sm.b.qh[row * QHS + part * 32 + j * 4]) = s;
        }
#pragma unroll
        for (int t = 0; t < TOPK; ++t)
            sm.b.fi[row][part * TOPK + t] = li[t];
    }
    __syncthreads();
    // ---- rescore own 16 candidates with r0-bit-exact arithmetic ----
    // kinv: r0's 8x(16-dim fmaf chain) + ((s0+s1)+(s2+s3))+((s4+s5)+(s6+s7)) tree;
    // score: single 128-dim fmaf chain over qhat and (k * kinv) with per-element rounding.
    // unroll 2: overlap two candidates' load chains (pure dependency chains -> no reassociation).
    {
        int row = tid >> 2, part = tid & 3;
        const float* qh = &sm.b.qh[row * QHS];
#pragma unroll 2
        for (int t = 0; t < TOPK; ++t) {
            int idx = li[t];
            const float* kp = Kg + (size_t)idx * DIM;
            float sp[8];
#pragma unroll
            for (int p = 0; p < 8; ++p) {
                float s = 0.f;
#pragma unroll
                for (int j = 0; j < 4; ++j) {
                    float4 kv = *(const float4*)(kp + p * 16 + j * 4);
                    s = fmaf(kv.x, kv.x, s); s = fmaf(kv.y, kv.y, s);
                    s = fmaf(kv.z, kv.z, s); s = fmaf(kv.w, kv.w, s);
                }
                sp[p] = s;
            }
            float kss = ((sp[0] + sp[1]) + (sp[2] + sp[3])) +
                        ((sp[4] + sp[5]) + (sp[6] + sp[7]));
            float kinv = 1.0f / fmaxf(sqrtf(kss), 1e-6f);
            float acc = 0.f;
#pragma unroll
            for (int d4 = 0; d4 < 32; ++d4) {
                float4 qa = *(const float4*)(qh + d4 * 4);
                float4 kv = *(const float4*)(kp + d4 * 4);
                acc = fmaf(qa.x, kv.x * kinv, acc);
                acc = fmaf(qa.y, kv.y * kinv, acc);
                acc = fmaf(qa.z, kv.z * kinv, acc);
                acc = fmaf(qa.w, kv.w * kinv, acc);
            }
            sm.b.fs[row][part * TOPK + t] = acc;
        }
    }
    __syncthreads();
    // final selection: one wave per 16 rows; 16 rounds of wave-max over 64 cands.
    // Tie-break by SMALLEST index (matches jax.lax.top_k stability).
    {
        int wv = tid >> 6, lane = tid & 63;
        for (int rr = 0; rr < 16; ++rr) {
            int row = wv * 16 + rr;
            float s = sm.b.fs[row][lane];
            int  id = sm.b.fi[row][lane];
#pragma unroll 1
            for (int it = 0; it < TOPK; ++it) {
                float m = s;
#pragma unroll
                for (int off = 32; off >= 1; off >>= 1)
                    m = fmaxf(m, __shfl_xor(m, off));
                int cand = (s == m) ? id : 0x7FFFFFFF;
#pragma unroll
                for (int off = 32; off >= 1; off >>= 1)
                    cand = min(cand, __shfl_xor(cand, off));
                if (lane == 0) { sm.b.tks[row][it] = m; sm.b.tki[row][it] = cand; }
                if (s == m && id == cand) s = -3e38f;   // pool indices unique -> removes one
            }
        }
    }
    __syncthreads();
    // ---- epilogue: gather V, weighted sum (descending order = ref order), gate blend ----
    {
        int row = tid >> 2, part = tid & 3;
        float4 acc[8];
#pragma unroll
        for (int j = 0; j < 8; ++j) acc[j] = make_float4(0.f, 0.f, 0.f, 0.f);
#pragma unroll 1
        for (int t = 0; t < TOPK; ++t) {
            float s = sm.b.tks[row][t];
            int idx = sm.b.tki[row][t] & (NMEM - 1);
            const float* vp = Vg + (size_t)idx * DIM + part * 32;
#pragma unroll
            for (int j = 0; j < 8; ++j) {
                float4 v = *(const float4*)(vp + j * 4);
                acc[j].x = fmaf(s, v.x, acc[j].x);
                acc[j].y = fmaf(s, v.y, acc[j].y);
                acc[j].z = fmaf(s, v.z, acc[j].z);
                acc[j].w = fmaf(s, v.w, acc[j].w);
            }
        }
        float g = 1.0f / (1.0f + expf(-gate[h]));
        float og = 1.0f - g;
        size_t ob = ((size_t)h * SEQ + q0 + row) * DIM + part * 32;
#pragma unroll
        for (int j = 0; j < 8; ++j) {
            float4 o = *(const float4*)(outputs + ob + j * 4);
            float4 r;
            r.x = g * acc[j].x + og * o.x;
            r.y = g * acc[j].y + og * o.y;
            r.z = g * acc[j].z + og * o.z;
            r.w = g * acc[j].w + og * o.w;
            *(float4*)(out + ob + j * 4) = r;
        }
    }
}

extern "C" void kernel_launch(void* const* d_in, const int* in_sizes, int n_in,
                              void* d_out, int out_size, void* d_ws, size_t ws_size,
                              hipStream_t stream) {
    (void)in_sizes; (void)n_in; (void)out_size; (void)d_ws; (void)ws_size;
    const float* query   = (const float*)d_in[1];
    const float* outputs = (const float*)d_in[4];
    const float* gate    = (const float*)d_in[5];
    const float* kmem    = (const float*)d_in[6];
    const float* vmem    = (const float*)d_in[7];
    float* out = (float*)d_out;
    dim3 grid(NH * (SEQ / TQ));  // 256 workgroups, exactly 1 per CU
    praxis_fused<<<grid, NTHR, 0, stream>>>(query, outputs, gate, kmem, vmem, out);
}